// Round 10
// baseline (127.978 us; speedup 1.0000x reference)
//
#include <hip/hip_runtime.h>
#include <hip/hip_bf16.h>

typedef __attribute__((ext_vector_type(4))) float f32x4;

#define TPB 256

// ---- ws layout (float offsets) ----
#define IN1F   0
#define IN2F   1120
#define HN1F   2240
#define HN2F   4288
#define L1OUT  6336
#define L3OUT  11456
#define GH1    16576
#define GH2    22720
#define GI1    28864
#define GI2    35008
#define H1OFF  41152
#define H2OFF  43200
#define T1OFF  45248
#define T2OFF  49344
// total 53440 floats = 213,760 bytes
// NOTE: GI1+6144 == GI2, so GI region is one contiguous 12288-float span.

// ---- asm load bursts (round-7-verified; vmcnt(0) inside the block) ----

__device__ __forceinline__ void burst2(const float* a,
                                       f32x4& w0, f32x4& w1)
{
    asm volatile(
        "global_load_dwordx4 %0, %2, off\n\t"
        "global_load_dwordx4 %1, %2, off offset:1024\n\t"
        "s_waitcnt vmcnt(0)"
        : "=&v"(w0), "=&v"(w1)
        : "v"(a) : "memory");
}

__device__ __forceinline__ void burst4(const float* a,
                                       f32x4& w0, f32x4& w1, f32x4& w2, f32x4& w3)
{
    asm volatile(
        "global_load_dwordx4 %0, %4, off\n\t"
        "global_load_dwordx4 %1, %4, off offset:1024\n\t"
        "global_load_dwordx4 %2, %4, off offset:2048\n\t"
        "global_load_dwordx4 %3, %4, off offset:3072\n\t"
        "s_waitcnt vmcnt(0)"
        : "=&v"(w0), "=&v"(w1), "=&v"(w2), "=&v"(w3)
        : "v"(a) : "memory");
}

__device__ __forceinline__ float dot4(const f32x4& w, const f32x4& x) {
    return w[0]*x[0] + w[1]*x[1] + w[2]*x[2] + w[3]*x[3];
}

__device__ __forceinline__ float wave_reduce(float acc) {
#pragma unroll
    for (int off = 32; off; off >>= 1) acc += __shfl_xor(acc, off, 64);
    return acc;
}

__device__ __forceinline__ void stage_x(const float* __restrict__ x, float* xl, int K)
{
    for (int i = threadIdx.x; i < (K >> 2); i += TPB)
        ((f32x4*)xl)[i] = ((const f32x4*)x)[i];
    __syncthreads();
}

// ---- row-sequential matvecs (round-8/9 structure, passing) ----

template <int ROWS>
__device__ __forceinline__ void mv2048(
    const float* __restrict__ W, const float* __restrict__ bias,
    float* xl, float* red, int row0, float* __restrict__ y, int act)
{
    const int wid  = threadIdx.x >> 6;
    const int lane = threadIdx.x & 63;
    const int c0   = lane * 4;
    const float* xw = xl + wid * 512 + c0;

#pragma unroll
    for (int r = 0; r < ROWS; ++r) {
        const float* seg = W + (size_t)(row0 + r) * 2048 + wid * 512 + c0;
        f32x4 w0, w1;
        burst2(seg, w0, w1);
        float acc = dot4(w0, *reinterpret_cast<const f32x4*>(xw))
                  + dot4(w1, *reinterpret_cast<const f32x4*>(xw + 256));
        acc = wave_reduce(acc);
        if (lane == 0) red[r * 4 + wid] = acc;
        __syncthreads();
    }
    if (threadIdx.x < ROWS) {
        int t = threadIdx.x;
        float v = red[t*4] + red[t*4+1] + red[t*4+2] + red[t*4+3] + bias[row0 + t];
        if (act) v = fmaxf(v, 0.f);
        y[row0 + t] = v;
    }
}

template <int ROWS>
__device__ __forceinline__ void mv4096(
    const float* __restrict__ W, const float* __restrict__ bias,
    float* xl, float* red, int row0, float* __restrict__ y, int act)
{
    const int wid  = threadIdx.x >> 6;
    const int lane = threadIdx.x & 63;
    const int c0   = lane * 4;
    const float* xw = xl + wid * 1024 + c0;

#pragma unroll
    for (int r = 0; r < ROWS; ++r) {
        const float* seg = W + (size_t)(row0 + r) * 4096 + wid * 1024 + c0;
        f32x4 w0, w1, w2, w3;
        burst4(seg, w0, w1, w2, w3);
        float acc = dot4(w0, *reinterpret_cast<const f32x4*>(xw))
                  + dot4(w1, *reinterpret_cast<const f32x4*>(xw + 256))
                  + dot4(w2, *reinterpret_cast<const f32x4*>(xw + 512))
                  + dot4(w3, *reinterpret_cast<const f32x4*>(xw + 768));
        acc = wave_reduce(acc);
        if (lane == 0) red[r * 4 + wid] = acc;
        __syncthreads();
    }
    if (threadIdx.x < ROWS) {
        int t = threadIdx.x;
        float v = red[t*4] + red[t*4+1] + red[t*4+2] + red[t*4+3] + bias[row0 + t];
        if (act) v = fmaxf(v, 0.f);
        y[row0 + t] = v;
    }
}

// K=1120: wave-per-row; burst4 covers 1024 floats, tail 96 in plain HIP.
__device__ __forceinline__ void mv1120(
    const float* __restrict__ W, const float* __restrict__ bias,
    float* xl, int row0, float* __restrict__ y, int act)
{
    const int wid  = threadIdx.x >> 6;
    const int lane = threadIdx.x & 63;
    const int c0   = lane * 4;

#pragma unroll
    for (int step = 0; step < 2; ++step) {
        const int rr = row0 + step * 4 + wid;
        const float* Wr = W + (size_t)rr * 1120;
        f32x4 w0, w1, w2, w3;
        burst4(Wr + c0, w0, w1, w2, w3);
        float acc = dot4(w0, *reinterpret_cast<const f32x4*>(xl + c0))
                  + dot4(w1, *reinterpret_cast<const f32x4*>(xl + 256 + c0))
                  + dot4(w2, *reinterpret_cast<const f32x4*>(xl + 512 + c0))
                  + dot4(w3, *reinterpret_cast<const f32x4*>(xl + 768 + c0));
        if (c0 < 96) {
            const f32x4 wt = *reinterpret_cast<const f32x4*>(Wr + 1024 + c0);
            const f32x4 xt = *reinterpret_cast<const f32x4*>(xl + 1024 + c0);
            acc += dot4(wt, xt);
        }
        acc = wave_reduce(acc);
        if (lane == 0) {
            float v = acc + bias[rr];
            if (act) v = fmaxf(v, 0.f);
            y[rr] = v;
        }
    }
}

// ---- stage 0: build input1/input2 + zero the GI accumulators ----
// grid = 48 * 256 = 12288 threads
__global__ void k_prep(const float* __restrict__ state_inno,
                       const float* __restrict__ obs_inno,
                       const float* __restrict__ diff_state,
                       const float* __restrict__ diff_obs,
                       const float* __restrict__ lin_err,
                       const float* __restrict__ jac,
                       float* __restrict__ ws)
{
    int i = blockIdx.x * blockDim.x + threadIdx.x;   // 0..12287
    if (i < 1120) {
        float v;
        if (i < 32)       v = state_inno[i];
        else if (i < 64)  v = diff_state[i - 32];
        else if (i < 96)  v = lin_err[i - 64];
        else              v = jac[i - 96];
        ws[IN1F + i] = v;
        float v2;
        if (i < 32)       v2 = obs_inno[i];
        else if (i < 64)  v2 = diff_obs[i - 32];
        else              v2 = v;  // lin_err / jacobian shared
        ws[IN2F + i] = v2;
    }
    ws[GI1 + i] = 0.f;   // GI1..GI1+12288 contiguous (covers GI1 and GI2)
}

// ---- stage A: l1, l3 (5120x1120, relu) + Whh@hn (6144x2048) x2 ----
// grid = 640 + 640 + 768 + 768 = 2816 (8 rows/block)
__global__ void __launch_bounds__(TPB)
k_stageA(const float* l1_W, const float* l1_b,
         const float* l3_W, const float* l3_b,
         const float* Whh1, const float* bhh1,
         const float* Whh2, const float* bhh2,
         const float* hn1, const float* hn2,
         float* ws)
{
    __shared__ float xl[2048];
    __shared__ float red[8 * 4];
    int bid = blockIdx.x;
    if (bid < 640) {
        stage_x(ws + IN1F, xl, 1120);
        mv1120(l1_W, l1_b, xl, bid * 8, ws + L1OUT, 1);
    } else if (bid < 1280) {
        stage_x(ws + IN2F, xl, 1120);
        mv1120(l3_W, l3_b, xl, (bid - 640) * 8, ws + L3OUT, 1);
    } else if (bid < 2048) {
        stage_x(hn1, xl, 2048);
        mv2048<8>(Whh1, bhh1, xl, red, (bid - 1280) * 8, ws + GH1, 0);
    } else {
        stage_x(hn2, xl, 2048);
        mv2048<8>(Whh2, bhh2, xl, red, (bid - 2048) * 8, ws + GH2, 0);
    }
}

// ---- stage B: ROLLING-FRONT partial-product kernel ----
// Treat [Wih1;Wih2] (2 x 6144 x 5120 f32 = 252MB) as 245760 chunks of 1KB.
// Flat wave g (8192 total) processes chunk c = t*8192 + g -> at any instant
// the whole chip reads ONE dense ~8MB window (the fillBuffer/m13-copy
// pattern that runs at 6-7 TB/s, vs 1.7 for our per-block scattered fronts).
// Each chunk: dot4 vs LDS x, wave shfl-reduce, lane0 atomicAdd into GI.
__global__ void __launch_bounds__(TPB)
k_partB(const float* __restrict__ Wih1, const float* __restrict__ Wih2,
        float* __restrict__ ws)
{
    __shared__ float xl[2 * 5120];   // 40KB: both x vectors
    for (int i = threadIdx.x; i < 1280; i += TPB)
        ((f32x4*)xl)[i] = ((const f32x4*)(ws + L1OUT))[i];
    for (int i = threadIdx.x; i < 1280; i += TPB)
        ((f32x4*)(xl + 5120))[i] = ((const f32x4*)(ws + L3OUT))[i];
    __syncthreads();

    const int wid  = threadIdx.x >> 6;
    const int lane = threadIdx.x & 63;
    const int g    = blockIdx.x * 4 + wid;   // 0..8191
    const int c4   = lane * 4;

#pragma unroll 2
    for (int t = 0; t < 30; ++t) {
        const int c  = t * 8192 + g;          // 0..245759
        const int m  = (c >= 122880) ? 1 : 0; // which matrix
        const int cl = c - m * 122880;
        const int row = cl / 20;              // 0..6143
        const int pos = cl - row * 20;        // 0..19
        const float* Wb = m ? Wih2 : Wih1;
        const f32x4 w = __builtin_nontemporal_load(
            reinterpret_cast<const f32x4*>(Wb + (size_t)row * 5120 + pos * 256 + c4));
        const f32x4 xv = *reinterpret_cast<const f32x4*>(xl + m * 5120 + pos * 256 + c4);
        float acc = dot4(w, xv);
        acc = wave_reduce(acc);
        if (lane == 0)
            atomicAdd(ws + (m ? GI2 : GI1) + row, acc);
    }
}

// ---- stage C: GRU gate combine (bias bih added here now) ----
__global__ void k_gru(const float* __restrict__ hn1,
                      const float* __restrict__ hn2,
                      const float* __restrict__ bih1,
                      const float* __restrict__ bih2,
                      float* __restrict__ ws)
{
    int i = blockIdx.x * blockDim.x + threadIdx.x;  // 0..4095
    int b = i >> 11, j = i & 2047;
    const float* gi = ws + (b ? GI2 : GI1);
    const float* gh = ws + (b ? GH2 : GH1);
    const float* bi = b ? bih2 : bih1;
    const float* hn = b ? hn2 : hn1;
    float r = 1.f / (1.f + expf(-(gi[j] + bi[j] + gh[j])));
    float z = 1.f / (1.f + expf(-(gi[2048 + j] + bi[2048 + j] + gh[2048 + j])));
    float n = tanhf(gi[4096 + j] + bi[4096 + j] + r * gh[4096 + j]);
    float h = (1.f - z) * n + z * hn[j];
    ws[(b ? H2OFF : H1OFF) + j] = h;
}

// ---- stage D: l2_W1 / l4_W1 (4096x2048, relu). grid = 512 + 512 ----
__global__ void __launch_bounds__(TPB)
k_stageD(const float* W21, const float* b21,
         const float* W41, const float* b41,
         float* ws)
{
    __shared__ float xl[2048];
    __shared__ float red[8 * 4];
    int bid = blockIdx.x;
    if (bid < 512) {
        stage_x(ws + H1OFF, xl, 2048);
        mv2048<8>(W21, b21, xl, red, bid * 8, ws + T1OFF, 1);
    } else {
        stage_x(ws + H2OFF, xl, 2048);
        mv2048<8>(W41, b41, xl, red, (bid - 512) * 8, ws + T2OFF, 1);
    }
}

// ---- stage E: l2_W2 / l4_W2 (1024x4096) -> f32 out. 2 rows/block, grid 1024 ----
__global__ void __launch_bounds__(TPB)
k_stageE(const float* __restrict__ W22, const float* __restrict__ b22,
         const float* __restrict__ W42, const float* __restrict__ b42,
         const float* __restrict__ ws, float* __restrict__ out)
{
    __shared__ float xl[4096];
    __shared__ float red[2 * 4];
    int bid = blockIdx.x;
    if (bid < 512) {
        stage_x(ws + T1OFF, xl, 4096);
        mv4096<2>(W22, b22, xl, red, bid * 2, out, 0);
    } else {
        stage_x(ws + T2OFF, xl, 4096);
        mv4096<2>(W42, b42, xl, red, (bid - 512) * 2, out + 1024, 0);
    }
}

extern "C" void kernel_launch(void* const* d_in, const int* in_sizes, int n_in,
                              void* d_out, int out_size, void* d_ws, size_t ws_size,
                              hipStream_t stream)
{
    const float* state_inno = (const float*)d_in[0];
    const float* obs_inno   = (const float*)d_in[1];
    const float* diff_state = (const float*)d_in[2];
    const float* diff_obs   = (const float*)d_in[3];
    const float* lin_err    = (const float*)d_in[4];
    const float* jac        = (const float*)d_in[5];
    const float* l1_W  = (const float*)d_in[6];
    const float* l1_b  = (const float*)d_in[7];
    const float* g1Wih = (const float*)d_in[8];
    const float* g1Whh = (const float*)d_in[9];
    const float* g1bih = (const float*)d_in[10];
    const float* g1bhh = (const float*)d_in[11];
    const float* l2_W1 = (const float*)d_in[12];
    const float* l2_b1 = (const float*)d_in[13];
    const float* l2_W2 = (const float*)d_in[14];
    const float* l2_b2 = (const float*)d_in[15];
    const float* l3_W  = (const float*)d_in[16];
    const float* l3_b  = (const float*)d_in[17];
    const float* g2Wih = (const float*)d_in[18];
    const float* g2Whh = (const float*)d_in[19];
    const float* g2bih = (const float*)d_in[20];
    const float* g2bhh = (const float*)d_in[21];
    const float* l4_W1 = (const float*)d_in[22];
    const float* l4_b1 = (const float*)d_in[23];
    const float* l4_W2 = (const float*)d_in[24];
    const float* l4_b2 = (const float*)d_in[25];
    const float* hn1   = (const float*)d_in[26];
    const float* hn2   = (const float*)d_in[27];

    float* ws = (float*)d_ws;
    float* out = (float*)d_out;

    hipLaunchKernelGGL(k_prep, dim3(48), dim3(TPB), 0, stream,
                       state_inno, obs_inno, diff_state, diff_obs, lin_err, jac, ws);

    hipLaunchKernelGGL(k_stageA, dim3(2816), dim3(TPB), 0, stream,
                       l1_W, l1_b, l3_W, l3_b, g1Whh, g1bhh, g2Whh, g2bhh,
                       hn1, hn2, ws);

    hipLaunchKernelGGL(k_partB, dim3(2048), dim3(TPB), 0, stream,
                       g1Wih, g2Wih, ws);

    hipLaunchKernelGGL(k_gru, dim3(16), dim3(TPB), 0, stream,
                       hn1, hn2, g1bih, g2bih, ws);

    hipLaunchKernelGGL(k_stageD, dim3(1024), dim3(TPB), 0, stream,
                       l2_W1, l2_b1, l4_W1, l4_b1, ws);

    hipLaunchKernelGGL(k_stageE, dim3(1024), dim3(TPB), 0, stream,
                       l2_W2, l2_b2, l4_W2, l4_b2, ws, out);
}

// Round 11
// 93.788 us; speedup vs baseline: 1.3645x; 1.3645x over previous
//
#include <hip/hip_runtime.h>
#include <hip/hip_bf16.h>

typedef __attribute__((ext_vector_type(4))) float f32x4;

#define TPB 256

// ---- ws layout (float offsets) ----
#define IN1F   0
#define IN2F   1120
#define L1OUT  6336
#define L3OUT  11456
#define GH1    16576
#define GH2    22720
#define GI1    28864
#define GI2    35008
#define H1OFF  41152
#define H2OFF  43200
#define T1OFF  45248
#define T2OFF  49344
// total 53440 floats = 213,760 bytes

// ---- asm load bursts (round-7-verified; vmcnt(0) inside the block) ----

__device__ __forceinline__ void burst2(const float* a,
                                       f32x4& w0, f32x4& w1)
{
    asm volatile(
        "global_load_dwordx4 %0, %2, off\n\t"
        "global_load_dwordx4 %1, %2, off offset:1024\n\t"
        "s_waitcnt vmcnt(0)"
        : "=&v"(w0), "=&v"(w1)
        : "v"(a) : "memory");
}

__device__ __forceinline__ void burst4(const float* a,
                                       f32x4& w0, f32x4& w1, f32x4& w2, f32x4& w3)
{
    asm volatile(
        "global_load_dwordx4 %0, %4, off\n\t"
        "global_load_dwordx4 %1, %4, off offset:1024\n\t"
        "global_load_dwordx4 %2, %4, off offset:2048\n\t"
        "global_load_dwordx4 %3, %4, off offset:3072\n\t"
        "s_waitcnt vmcnt(0)"
        : "=&v"(w0), "=&v"(w1), "=&v"(w2), "=&v"(w3)
        : "v"(a) : "memory");
}

// Non-temporal burst for the Wih stream (252MB, L3-thrashing): keep it from
// evicting the L3-friendly 247MB (l1/l3/Whh/D/E weights). Round-9-verified.
__device__ __forceinline__ void burst5_nt(const float* a, const float* a4,
                                          f32x4& w0, f32x4& w1, f32x4& w2,
                                          f32x4& w3, f32x4& w4)
{
    asm volatile(
        "global_load_dwordx4 %0, %5, off nt\n\t"
        "global_load_dwordx4 %1, %5, off offset:1024 nt\n\t"
        "global_load_dwordx4 %2, %5, off offset:2048 nt\n\t"
        "global_load_dwordx4 %3, %5, off offset:3072 nt\n\t"
        "global_load_dwordx4 %4, %6, off nt\n\t"
        "s_waitcnt vmcnt(0)"
        : "=&v"(w0), "=&v"(w1), "=&v"(w2), "=&v"(w3), "=&v"(w4)
        : "v"(a), "v"(a4) : "memory");
}

__device__ __forceinline__ float dot4(const f32x4& w, const f32x4& x) {
    return w[0]*x[0] + w[1]*x[1] + w[2]*x[2] + w[3]*x[3];
}

__device__ __forceinline__ float wave_reduce(float acc) {
#pragma unroll
    for (int off = 32; off; off >>= 1) acc += __shfl_xor(acc, off, 64);
    return acc;
}

__device__ __forceinline__ void stage_x(const float* __restrict__ x, float* xl, int K)
{
    for (int i = threadIdx.x; i < (K >> 2); i += TPB)
        ((f32x4*)xl)[i] = ((const f32x4*)x)[i];
    __syncthreads();
}

// ---- row-sequential matvecs (round-8/9 structure, passing) ----

// K=5120, nt weight reads: wave w takes quarter [w*1280, +1280) of the row.
template <int ROWS>
__device__ __forceinline__ void mv5120(
    const float* __restrict__ W, const float* __restrict__ bias,
    float* xl, float* red, int row0, float* __restrict__ y, int act)
{
    const int wid  = threadIdx.x >> 6;
    const int lane = threadIdx.x & 63;
    const int c0   = lane * 4;
    const float* xw = xl + wid * 1280 + c0;

#pragma unroll
    for (int r = 0; r < ROWS; ++r) {
        const float* seg = W + (size_t)(row0 + r) * 5120 + wid * 1280 + c0;
        f32x4 w0, w1, w2, w3, w4;
        burst5_nt(seg, seg + 1024, w0, w1, w2, w3, w4);
        float acc = dot4(w0, *reinterpret_cast<const f32x4*>(xw))
                  + dot4(w1, *reinterpret_cast<const f32x4*>(xw + 256))
                  + dot4(w2, *reinterpret_cast<const f32x4*>(xw + 512))
                  + dot4(w3, *reinterpret_cast<const f32x4*>(xw + 768))
                  + dot4(w4, *reinterpret_cast<const f32x4*>(xw + 1024));
        acc = wave_reduce(acc);
        if (lane == 0) red[r * 4 + wid] = acc;
        __syncthreads();
    }
    if (threadIdx.x < ROWS) {
        int t = threadIdx.x;
        float v = red[t*4] + red[t*4+1] + red[t*4+2] + red[t*4+3] + bias[row0 + t];
        if (act) v = fmaxf(v, 0.f);
        y[row0 + t] = v;
    }
}

template <int ROWS>
__device__ __forceinline__ void mv2048(
    const float* __restrict__ W, const float* __restrict__ bias,
    float* xl, float* red, int row0, float* __restrict__ y, int act)
{
    const int wid  = threadIdx.x >> 6;
    const int lane = threadIdx.x & 63;
    const int c0   = lane * 4;
    const float* xw = xl + wid * 512 + c0;

#pragma unroll
    for (int r = 0; r < ROWS; ++r) {
        const float* seg = W + (size_t)(row0 + r) * 2048 + wid * 512 + c0;
        f32x4 w0, w1;
        burst2(seg, w0, w1);
        float acc = dot4(w0, *reinterpret_cast<const f32x4*>(xw))
                  + dot4(w1, *reinterpret_cast<const f32x4*>(xw + 256));
        acc = wave_reduce(acc);
        if (lane == 0) red[r * 4 + wid] = acc;
        __syncthreads();
    }
    if (threadIdx.x < ROWS) {
        int t = threadIdx.x;
        float v = red[t*4] + red[t*4+1] + red[t*4+2] + red[t*4+3] + bias[row0 + t];
        if (act) v = fmaxf(v, 0.f);
        y[row0 + t] = v;
    }
}

template <int ROWS>
__device__ __forceinline__ void mv4096(
    const float* __restrict__ W, const float* __restrict__ bias,
    float* xl, float* red, int row0, float* __restrict__ y, int act)
{
    const int wid  = threadIdx.x >> 6;
    const int lane = threadIdx.x & 63;
    const int c0   = lane * 4;
    const float* xw = xl + wid * 1024 + c0;

#pragma unroll
    for (int r = 0; r < ROWS; ++r) {
        const float* seg = W + (size_t)(row0 + r) * 4096 + wid * 1024 + c0;
        f32x4 w0, w1, w2, w3;
        burst4(seg, w0, w1, w2, w3);
        float acc = dot4(w0, *reinterpret_cast<const f32x4*>(xw))
                  + dot4(w1, *reinterpret_cast<const f32x4*>(xw + 256))
                  + dot4(w2, *reinterpret_cast<const f32x4*>(xw + 512))
                  + dot4(w3, *reinterpret_cast<const f32x4*>(xw + 768));
        acc = wave_reduce(acc);
        if (lane == 0) red[r * 4 + wid] = acc;
        __syncthreads();
    }
    if (threadIdx.x < ROWS) {
        int t = threadIdx.x;
        float v = red[t*4] + red[t*4+1] + red[t*4+2] + red[t*4+3] + bias[row0 + t];
        if (act) v = fmaxf(v, 0.f);
        y[row0 + t] = v;
    }
}

// K=1120: wave-per-row; burst4 covers 1024 floats, tail 96 in plain HIP.
__device__ __forceinline__ void mv1120(
    const float* __restrict__ W, const float* __restrict__ bias,
    float* xl, int row0, float* __restrict__ y, int act)
{
    const int wid  = threadIdx.x >> 6;
    const int lane = threadIdx.x & 63;
    const int c0   = lane * 4;

#pragma unroll
    for (int step = 0; step < 2; ++step) {
        const int rr = row0 + step * 4 + wid;
        const float* Wr = W + (size_t)rr * 1120;
        f32x4 w0, w1, w2, w3;
        burst4(Wr + c0, w0, w1, w2, w3);
        float acc = dot4(w0, *reinterpret_cast<const f32x4*>(xl + c0))
                  + dot4(w1, *reinterpret_cast<const f32x4*>(xl + 256 + c0))
                  + dot4(w2, *reinterpret_cast<const f32x4*>(xl + 512 + c0))
                  + dot4(w3, *reinterpret_cast<const f32x4*>(xl + 768 + c0));
        if (c0 < 96) {
            const f32x4 wt = *reinterpret_cast<const f32x4*>(Wr + 1024 + c0);
            const f32x4 xt = *reinterpret_cast<const f32x4*>(xl + 1024 + c0);
            acc += dot4(wt, xt);
        }
        acc = wave_reduce(acc);
        if (lane == 0) {
            float v = acc + bias[rr];
            if (act) v = fmaxf(v, 0.f);
            y[rr] = v;
        }
    }
}

// ---- stage 0: build input1/input2 ----
__global__ void k_prep(const float* __restrict__ state_inno,
                       const float* __restrict__ obs_inno,
                       const float* __restrict__ diff_state,
                       const float* __restrict__ diff_obs,
                       const float* __restrict__ lin_err,
                       const float* __restrict__ jac,
                       float* __restrict__ ws)
{
    int i = blockIdx.x * blockDim.x + threadIdx.x;
    if (i < 1120) {
        float v;
        if (i < 32)       v = state_inno[i];
        else if (i < 64)  v = diff_state[i - 32];
        else if (i < 96)  v = lin_err[i - 64];
        else              v = jac[i - 96];
        ws[IN1F + i] = v;
        float v2;
        if (i < 32)       v2 = obs_inno[i];
        else if (i < 64)  v2 = diff_obs[i - 32];
        else              v2 = v;  // lin_err / jacobian shared
        ws[IN2F + i] = v2;
    }
}

// ---- stage 1: l1 / l3 (5120x1120, relu). grid = 640 + 640 ----
__global__ void __launch_bounds__(TPB)
k_l1l3(const float* l1_W, const float* l1_b,
       const float* l3_W, const float* l3_b,
       float* ws)
{
    __shared__ float xl[1120];
    int bid = blockIdx.x;
    if (bid < 640) {
        stage_x(ws + IN1F, xl, 1120);
        mv1120(l1_W, l1_b, xl, bid * 8, ws + L1OUT, 1);
    } else {
        stage_x(ws + IN2F, xl, 1120);
        mv1120(l3_W, l3_b, xl, (bid - 640) * 8, ws + L3OUT, 1);
    }
}

// ---- stage 2: MERGED gates kernel — Wih (nt, HBM-bound) INTERLEAVED with
// Whh (L3-friendly, independent). 2048 Wih-works (6 rows) + 1536 Whh-works
// (8 rows) = 3584 blocks; bid%7 maps 4:3 so both kinds are co-resident from
// the first dispatch wave -> Whh rides in the shadow of Wih's miss stream.
__global__ void __launch_bounds__(TPB)
k_gates(const float* Wih1, const float* bih1,
        const float* Wih2, const float* bih2,
        const float* Whh1, const float* bhh1,
        const float* Whh2, const float* bhh2,
        const float* hn1, const float* hn2,
        float* ws)
{
    __shared__ float xl[5120];
    __shared__ float red[8 * 4];
    const int g = blockIdx.x / 7;
    const int r = blockIdx.x % 7;
    if (r < 4) {
        int w = g * 4 + r;           // 0..2047
        if (w < 1024) {
            stage_x(ws + L1OUT, xl, 5120);
            mv5120<6>(Wih1, bih1, xl, red, w * 6, ws + GI1, 0);
        } else {
            stage_x(ws + L3OUT, xl, 5120);
            mv5120<6>(Wih2, bih2, xl, red, (w - 1024) * 6, ws + GI2, 0);
        }
    } else {
        int w = g * 3 + (r - 4);     // 0..1535
        if (w < 768) {
            stage_x(hn1, xl, 2048);
            mv2048<8>(Whh1, bhh1, xl, red, w * 8, ws + GH1, 0);
        } else {
            stage_x(hn2, xl, 2048);
            mv2048<8>(Whh2, bhh2, xl, red, (w - 768) * 8, ws + GH2, 0);
        }
    }
}

// ---- stage 3: GRU gate combine ----
__global__ void k_gru(const float* __restrict__ hn1,
                      const float* __restrict__ hn2,
                      float* __restrict__ ws)
{
    int i = blockIdx.x * blockDim.x + threadIdx.x;  // 0..4095
    int b = i >> 11, j = i & 2047;
    const float* gi = ws + (b ? GI2 : GI1);
    const float* gh = ws + (b ? GH2 : GH1);
    const float* hn = b ? hn2 : hn1;
    float r = 1.f / (1.f + expf(-(gi[j] + gh[j])));
    float z = 1.f / (1.f + expf(-(gi[2048 + j] + gh[2048 + j])));
    float n = tanhf(gi[4096 + j] + r * gh[4096 + j]);
    float h = (1.f - z) * n + z * hn[j];
    ws[(b ? H2OFF : H1OFF) + j] = h;
}

// ---- stage 4: l2_W1 / l4_W1 (4096x2048, relu). grid = 512 + 512 ----
__global__ void __launch_bounds__(TPB)
k_stageD(const float* W21, const float* b21,
         const float* W41, const float* b41,
         float* ws)
{
    __shared__ float xl[2048];
    __shared__ float red[8 * 4];
    int bid = blockIdx.x;
    if (bid < 512) {
        stage_x(ws + H1OFF, xl, 2048);
        mv2048<8>(W21, b21, xl, red, bid * 8, ws + T1OFF, 1);
    } else {
        stage_x(ws + H2OFF, xl, 2048);
        mv2048<8>(W41, b41, xl, red, (bid - 512) * 8, ws + T2OFF, 1);
    }
}

// ---- stage 5: l2_W2 / l4_W2 (1024x4096) -> f32 out. grid = 1024 ----
__global__ void __launch_bounds__(TPB)
k_stageE(const float* __restrict__ W22, const float* __restrict__ b22,
         const float* __restrict__ W42, const float* __restrict__ b42,
         const float* __restrict__ ws, float* __restrict__ out)
{
    __shared__ float xl[4096];
    __shared__ float red[2 * 4];
    int bid = blockIdx.x;
    if (bid < 512) {
        stage_x(ws + T1OFF, xl, 4096);
        mv4096<2>(W22, b22, xl, red, bid * 2, out, 0);
    } else {
        stage_x(ws + T2OFF, xl, 4096);
        mv4096<2>(W42, b42, xl, red, (bid - 512) * 2, out + 1024, 0);
    }
}

extern "C" void kernel_launch(void* const* d_in, const int* in_sizes, int n_in,
                              void* d_out, int out_size, void* d_ws, size_t ws_size,
                              hipStream_t stream)
{
    const float* state_inno = (const float*)d_in[0];
    const float* obs_inno   = (const float*)d_in[1];
    const float* diff_state = (const float*)d_in[2];
    const float* diff_obs   = (const float*)d_in[3];
    const float* lin_err    = (const float*)d_in[4];
    const float* jac        = (const float*)d_in[5];
    const float* l1_W  = (const float*)d_in[6];
    const float* l1_b  = (const float*)d_in[7];
    const float* g1Wih = (const float*)d_in[8];
    const float* g1Whh = (const float*)d_in[9];
    const float* g1bih = (const float*)d_in[10];
    const float* g1bhh = (const float*)d_in[11];
    const float* l2_W1 = (const float*)d_in[12];
    const float* l2_b1 = (const float*)d_in[13];
    const float* l2_W2 = (const float*)d_in[14];
    const float* l2_b2 = (const float*)d_in[15];
    const float* l3_W  = (const float*)d_in[16];
    const float* l3_b  = (const float*)d_in[17];
    const float* g2Wih = (const float*)d_in[18];
    const float* g2Whh = (const float*)d_in[19];
    const float* g2bih = (const float*)d_in[20];
    const float* g2bhh = (const float*)d_in[21];
    const float* l4_W1 = (const float*)d_in[22];
    const float* l4_b1 = (const float*)d_in[23];
    const float* l4_W2 = (const float*)d_in[24];
    const float* l4_b2 = (const float*)d_in[25];
    const float* hn1   = (const float*)d_in[26];
    const float* hn2   = (const float*)d_in[27];

    float* ws = (float*)d_ws;
    float* out = (float*)d_out;

    hipLaunchKernelGGL(k_prep, dim3(5), dim3(TPB), 0, stream,
                       state_inno, obs_inno, diff_state, diff_obs, lin_err, jac, ws);

    hipLaunchKernelGGL(k_l1l3, dim3(1280), dim3(TPB), 0, stream,
                       l1_W, l1_b, l3_W, l3_b, ws);

    hipLaunchKernelGGL(k_gates, dim3(3584), dim3(TPB), 0, stream,
                       g1Wih, g1bih, g2Wih, g2bih,
                       g1Whh, g1bhh, g2Whh, g2bhh, hn1, hn2, ws);

    hipLaunchKernelGGL(k_gru, dim3(16), dim3(TPB), 0, stream, hn1, hn2, ws);

    hipLaunchKernelGGL(k_stageD, dim3(1024), dim3(TPB), 0, stream,
                       l2_W1, l2_b1, l4_W1, l4_b1, ws);

    hipLaunchKernelGGL(k_stageE, dim3(1024), dim3(TPB), 0, stream,
                       l2_W2, l2_b2, l4_W2, l4_b2, ws, out);
}

// Round 12
// 93.262 us; speedup vs baseline: 1.3722x; 1.0056x over previous
//
#include <hip/hip_runtime.h>
#include <hip/hip_bf16.h>

typedef __attribute__((ext_vector_type(4))) float f32x4;

#define TPB 256

// ---- ws layout (float offsets) ----
#define IN1F   0
#define IN2F   1120
#define L1OUT  6336
#define L3OUT  11456
#define GH1    16576
#define GH2    22720
#define GI1    28864
#define GI2    35008
#define H1OFF  41152
#define H2OFF  43200
#define T1OFF  45248
#define T2OFF  49344
// total 53440 floats = 213,760 bytes

// counted-vmcnt wait + scheduling fence (rule #18: sched_barrier right after)
#define WAITVM(N) do { \
    asm volatile("s_waitcnt vmcnt(" #N ")" ::: "memory"); \
    __builtin_amdgcn_sched_barrier(0); \
} while (0)

// ---- asm load bursts (round-7-verified; vmcnt(0) inside the block) ----

__device__ __forceinline__ void burst2(const float* a,
                                       f32x4& w0, f32x4& w1)
{
    asm volatile(
        "global_load_dwordx4 %0, %2, off\n\t"
        "global_load_dwordx4 %1, %2, off offset:1024\n\t"
        "s_waitcnt vmcnt(0)"
        : "=&v"(w0), "=&v"(w1)
        : "v"(a) : "memory");
}

__device__ __forceinline__ void burst4(const float* a,
                                       f32x4& w0, f32x4& w1, f32x4& w2, f32x4& w3)
{
    asm volatile(
        "global_load_dwordx4 %0, %4, off\n\t"
        "global_load_dwordx4 %1, %4, off offset:1024\n\t"
        "global_load_dwordx4 %2, %4, off offset:2048\n\t"
        "global_load_dwordx4 %3, %4, off offset:3072\n\t"
        "s_waitcnt vmcnt(0)"
        : "=&v"(w0), "=&v"(w1), "=&v"(w2), "=&v"(w3)
        : "v"(a) : "memory");
}

// Non-temporal ISSUE-ONLY burst (NO waitcnt inside): outputs become valid
// only after a later WAITVM — used by the software-pipelined mv5120.
__device__ __forceinline__ void burst5_nt_issue(const float* a, const float* a4,
                                                f32x4& w0, f32x4& w1, f32x4& w2,
                                                f32x4& w3, f32x4& w4)
{
    asm volatile(
        "global_load_dwordx4 %0, %5, off nt\n\t"
        "global_load_dwordx4 %1, %5, off offset:1024 nt\n\t"
        "global_load_dwordx4 %2, %5, off offset:2048 nt\n\t"
        "global_load_dwordx4 %3, %5, off offset:3072 nt\n\t"
        "global_load_dwordx4 %4, %6, off nt"
        : "=&v"(w0), "=&v"(w1), "=&v"(w2), "=&v"(w3), "=&v"(w4)
        : "v"(a), "v"(a4) : "memory");
}

__device__ __forceinline__ float dot4(const f32x4& w, const f32x4& x) {
    return w[0]*x[0] + w[1]*x[1] + w[2]*x[2] + w[3]*x[3];
}

__device__ __forceinline__ float wave_reduce(float acc) {
#pragma unroll
    for (int off = 32; off; off >>= 1) acc += __shfl_xor(acc, off, 64);
    return acc;
}

__device__ __forceinline__ void stage_x(const float* __restrict__ x, float* xl, int K)
{
    for (int i = threadIdx.x; i < (K >> 2); i += TPB)
        ((f32x4*)xl)[i] = ((const f32x4*)x)[i];
    __syncthreads();
}

// ---- K=5120 SOFTWARE-PIPELINED (T4 counted-vmcnt): issue burst r+1 into the
// alternate register set BEFORE computing row r; wait vmcnt(5) not 0; no
// per-row barrier. Loads stay in flight ~100% of wave time.
template <int ROWS>
__device__ __forceinline__ void mv5120_pipe(
    const float* __restrict__ W, const float* __restrict__ bias,
    float* xl, float* red, int row0, float* __restrict__ y, int act)
{
    const int wid  = threadIdx.x >> 6;
    const int lane = threadIdx.x & 63;
    const int c0   = lane * 4;
    const float* xw = xl + wid * 1280 + c0;

    f32x4 a0, a1, a2, a3, a4;   // even rows
    f32x4 b0, b1, b2, b3, b4;   // odd rows

    {
        const float* seg = W + (size_t)row0 * 5120 + wid * 1280 + c0;
        burst5_nt_issue(seg, seg + 1024, a0, a1, a2, a3, a4);
    }

#pragma unroll
    for (int r = 0; r < ROWS; ++r) {
        if (r + 1 < ROWS) {
            const float* seg = W + (size_t)(row0 + r + 1) * 5120 + wid * 1280 + c0;
            if ((r & 1) == 0)
                burst5_nt_issue(seg, seg + 1024, b0, b1, b2, b3, b4);
            else
                burst5_nt_issue(seg, seg + 1024, a0, a1, a2, a3, a4);
            WAITVM(5);   // row r's 5 loads landed; row r+1's 5 stay in flight
        } else {
            WAITVM(0);
        }
        float acc;
        if ((r & 1) == 0)
            acc = dot4(a0, *reinterpret_cast<const f32x4*>(xw))
                + dot4(a1, *reinterpret_cast<const f32x4*>(xw + 256))
                + dot4(a2, *reinterpret_cast<const f32x4*>(xw + 512))
                + dot4(a3, *reinterpret_cast<const f32x4*>(xw + 768))
                + dot4(a4, *reinterpret_cast<const f32x4*>(xw + 1024));
        else
            acc = dot4(b0, *reinterpret_cast<const f32x4*>(xw))
                + dot4(b1, *reinterpret_cast<const f32x4*>(xw + 256))
                + dot4(b2, *reinterpret_cast<const f32x4*>(xw + 512))
                + dot4(b3, *reinterpret_cast<const f32x4*>(xw + 768))
                + dot4(b4, *reinterpret_cast<const f32x4*>(xw + 1024));
        acc = wave_reduce(acc);
        if (lane == 0) red[r * 4 + wid] = acc;
    }
    __syncthreads();
    if (threadIdx.x < ROWS) {
        int t = threadIdx.x;
        float v = red[t*4] + red[t*4+1] + red[t*4+2] + red[t*4+3] + bias[row0 + t];
        if (act) v = fmaxf(v, 0.f);
        y[row0 + t] = v;
    }
}

// ---- row-sequential matvecs (round-8/9/11 structure, passing) ----

template <int ROWS>
__device__ __forceinline__ void mv2048(
    const float* __restrict__ W, const float* __restrict__ bias,
    float* xl, float* red, int row0, float* __restrict__ y, int act)
{
    const int wid  = threadIdx.x >> 6;
    const int lane = threadIdx.x & 63;
    const int c0   = lane * 4;
    const float* xw = xl + wid * 512 + c0;

#pragma unroll
    for (int r = 0; r < ROWS; ++r) {
        const float* seg = W + (size_t)(row0 + r) * 2048 + wid * 512 + c0;
        f32x4 w0, w1;
        burst2(seg, w0, w1);
        float acc = dot4(w0, *reinterpret_cast<const f32x4*>(xw))
                  + dot4(w1, *reinterpret_cast<const f32x4*>(xw + 256));
        acc = wave_reduce(acc);
        if (lane == 0) red[r * 4 + wid] = acc;
        __syncthreads();
    }
    if (threadIdx.x < ROWS) {
        int t = threadIdx.x;
        float v = red[t*4] + red[t*4+1] + red[t*4+2] + red[t*4+3] + bias[row0 + t];
        if (act) v = fmaxf(v, 0.f);
        y[row0 + t] = v;
    }
}

template <int ROWS>
__device__ __forceinline__ void mv4096(
    const float* __restrict__ W, const float* __restrict__ bias,
    float* xl, float* red, int row0, float* __restrict__ y, int act)
{
    const int wid  = threadIdx.x >> 6;
    const int lane = threadIdx.x & 63;
    const int c0   = lane * 4;
    const float* xw = xl + wid * 1024 + c0;

#pragma unroll
    for (int r = 0; r < ROWS; ++r) {
        const float* seg = W + (size_t)(row0 + r) * 4096 + wid * 1024 + c0;
        f32x4 w0, w1, w2, w3;
        burst4(seg, w0, w1, w2, w3);
        float acc = dot4(w0, *reinterpret_cast<const f32x4*>(xw))
                  + dot4(w1, *reinterpret_cast<const f32x4*>(xw + 256))
                  + dot4(w2, *reinterpret_cast<const f32x4*>(xw + 512))
                  + dot4(w3, *reinterpret_cast<const f32x4*>(xw + 768));
        acc = wave_reduce(acc);
        if (lane == 0) red[r * 4 + wid] = acc;
        __syncthreads();
    }
    if (threadIdx.x < ROWS) {
        int t = threadIdx.x;
        float v = red[t*4] + red[t*4+1] + red[t*4+2] + red[t*4+3] + bias[row0 + t];
        if (act) v = fmaxf(v, 0.f);
        y[row0 + t] = v;
    }
}

// K=1120: wave-per-row; burst4 covers 1024 floats, tail 96 in plain HIP.
__device__ __forceinline__ void mv1120(
    const float* __restrict__ W, const float* __restrict__ bias,
    float* xl, int row0, float* __restrict__ y, int act)
{
    const int wid  = threadIdx.x >> 6;
    const int lane = threadIdx.x & 63;
    const int c0   = lane * 4;

#pragma unroll
    for (int step = 0; step < 2; ++step) {
        const int rr = row0 + step * 4 + wid;
        const float* Wr = W + (size_t)rr * 1120;
        f32x4 w0, w1, w2, w3;
        burst4(Wr + c0, w0, w1, w2, w3);
        float acc = dot4(w0, *reinterpret_cast<const f32x4*>(xl + c0))
                  + dot4(w1, *reinterpret_cast<const f32x4*>(xl + 256 + c0))
                  + dot4(w2, *reinterpret_cast<const f32x4*>(xl + 512 + c0))
                  + dot4(w3, *reinterpret_cast<const f32x4*>(xl + 768 + c0));
        if (c0 < 96) {
            const f32x4 wt = *reinterpret_cast<const f32x4*>(Wr + 1024 + c0);
            const f32x4 xt = *reinterpret_cast<const f32x4*>(xl + 1024 + c0);
            acc += dot4(wt, xt);
        }
        acc = wave_reduce(acc);
        if (lane == 0) {
            float v = acc + bias[rr];
            if (act) v = fmaxf(v, 0.f);
            y[rr] = v;
        }
    }
}

// ---- stage 0: build input1/input2 ----
__global__ void k_prep(const float* __restrict__ state_inno,
                       const float* __restrict__ obs_inno,
                       const float* __restrict__ diff_state,
                       const float* __restrict__ diff_obs,
                       const float* __restrict__ lin_err,
                       const float* __restrict__ jac,
                       float* __restrict__ ws)
{
    int i = blockIdx.x * blockDim.x + threadIdx.x;
    if (i < 1120) {
        float v;
        if (i < 32)       v = state_inno[i];
        else if (i < 64)  v = diff_state[i - 32];
        else if (i < 96)  v = lin_err[i - 64];
        else              v = jac[i - 96];
        ws[IN1F + i] = v;
        float v2;
        if (i < 32)       v2 = obs_inno[i];
        else if (i < 64)  v2 = diff_obs[i - 32];
        else              v2 = v;  // lin_err / jacobian shared
        ws[IN2F + i] = v2;
    }
}

// ---- stage 1: l1 / l3 (5120x1120, relu). grid = 640 + 640 ----
__global__ void __launch_bounds__(TPB)
k_l1l3(const float* l1_W, const float* l1_b,
       const float* l3_W, const float* l3_b,
       float* ws)
{
    __shared__ float xl[1120];
    int bid = blockIdx.x;
    if (bid < 640) {
        stage_x(ws + IN1F, xl, 1120);
        mv1120(l1_W, l1_b, xl, bid * 8, ws + L1OUT, 1);
    } else {
        stage_x(ws + IN2F, xl, 1120);
        mv1120(l3_W, l3_b, xl, (bid - 640) * 8, ws + L3OUT, 1);
    }
}

// ---- stage 2: MERGED gates kernel — Wih (nt, pipelined) + Whh (L3) ----
__global__ void __launch_bounds__(TPB)
k_gates(const float* Wih1, const float* bih1,
        const float* Wih2, const float* bih2,
        const float* Whh1, const float* bhh1,
        const float* Whh2, const float* bhh2,
        const float* hn1, const float* hn2,
        float* ws)
{
    __shared__ float xl[5120];
    __shared__ float red[8 * 4];
    const int g = blockIdx.x / 7;
    const int r = blockIdx.x % 7;
    if (r < 4) {
        int w = g * 4 + r;           // 0..2047
        if (w < 1024) {
            stage_x(ws + L1OUT, xl, 5120);
            mv5120_pipe<6>(Wih1, bih1, xl, red, w * 6, ws + GI1, 0);
        } else {
            stage_x(ws + L3OUT, xl, 5120);
            mv5120_pipe<6>(Wih2, bih2, xl, red, (w - 1024) * 6, ws + GI2, 0);
        }
    } else {
        int w = g * 3 + (r - 4);     // 0..1535
        if (w < 768) {
            stage_x(hn1, xl, 2048);
            mv2048<8>(Whh1, bhh1, xl, red, w * 8, ws + GH1, 0);
        } else {
            stage_x(hn2, xl, 2048);
            mv2048<8>(Whh2, bhh2, xl, red, (w - 768) * 8, ws + GH2, 0);
        }
    }
}

// ---- stage 3: GRU gate combine ----
__global__ void k_gru(const float* __restrict__ hn1,
                      const float* __restrict__ hn2,
                      float* __restrict__ ws)
{
    int i = blockIdx.x * blockDim.x + threadIdx.x;  // 0..4095
    int b = i >> 11, j = i & 2047;
    const float* gi = ws + (b ? GI2 : GI1);
    const float* gh = ws + (b ? GH2 : GH1);
    const float* hn = b ? hn2 : hn1;
    float r = 1.f / (1.f + expf(-(gi[j] + gh[j])));
    float z = 1.f / (1.f + expf(-(gi[2048 + j] + gh[2048 + j])));
    float n = tanhf(gi[4096 + j] + r * gh[4096 + j]);
    float h = (1.f - z) * n + z * hn[j];
    ws[(b ? H2OFF : H1OFF) + j] = h;
}

// ---- stage 4: l2_W1 / l4_W1 (4096x2048, relu). grid = 512 + 512 ----
__global__ void __launch_bounds__(TPB)
k_stageD(const float* W21, const float* b21,
         const float* W41, const float* b41,
         float* ws)
{
    __shared__ float xl[2048];
    __shared__ float red[8 * 4];
    int bid = blockIdx.x;
    if (bid < 512) {
        stage_x(ws + H1OFF, xl, 2048);
        mv2048<8>(W21, b21, xl, red, bid * 8, ws + T1OFF, 1);
    } else {
        stage_x(ws + H2OFF, xl, 2048);
        mv2048<8>(W41, b41, xl, red, (bid - 512) * 8, ws + T2OFF, 1);
    }
}

// ---- stage 5: l2_W2 / l4_W2 (1024x4096) -> f32 out. grid = 1024 ----
__global__ void __launch_bounds__(TPB)
k_stageE(const float* __restrict__ W22, const float* __restrict__ b22,
         const float* __restrict__ W42, const float* __restrict__ b42,
         const float* __restrict__ ws, float* __restrict__ out)
{
    __shared__ float xl[4096];
    __shared__ float red[2 * 4];
    int bid = blockIdx.x;
    if (bid < 512) {
        stage_x(ws + T1OFF, xl, 4096);
        mv4096<2>(W22, b22, xl, red, bid * 2, out, 0);
    } else {
        stage_x(ws + T2OFF, xl, 4096);
        mv4096<2>(W42, b42, xl, red, (bid - 512) * 2, out + 1024, 0);
    }
}

extern "C" void kernel_launch(void* const* d_in, const int* in_sizes, int n_in,
                              void* d_out, int out_size, void* d_ws, size_t ws_size,
                              hipStream_t stream)
{
    const float* state_inno = (const float*)d_in[0];
    const float* obs_inno   = (const float*)d_in[1];
    const float* diff_state = (const float*)d_in[2];
    const float* diff_obs   = (const float*)d_in[3];
    const float* lin_err    = (const float*)d_in[4];
    const float* jac        = (const float*)d_in[5];
    const float* l1_W  = (const float*)d_in[6];
    const float* l1_b  = (const float*)d_in[7];
    const float* g1Wih = (const float*)d_in[8];
    const float* g1Whh = (const float*)d_in[9];
    const float* g1bih = (const float*)d_in[10];
    const float* g1bhh = (const float*)d_in[11];
    const float* l2_W1 = (const float*)d_in[12];
    const float* l2_b1 = (const float*)d_in[13];
    const float* l2_W2 = (const float*)d_in[14];
    const float* l2_b2 = (const float*)d_in[15];
    const float* l3_W  = (const float*)d_in[16];
    const float* l3_b  = (const float*)d_in[17];
    const float* g2Wih = (const float*)d_in[18];
    const float* g2Whh = (const float*)d_in[19];
    const float* g2bih = (const float*)d_in[20];
    const float* g2bhh = (const float*)d_in[21];
    const float* l4_W1 = (const float*)d_in[22];
    const float* l4_b1 = (const float*)d_in[23];
    const float* l4_W2 = (const float*)d_in[24];
    const float* l4_b2 = (const float*)d_in[25];
    const float* hn1   = (const float*)d_in[26];
    const float* hn2   = (const float*)d_in[27];

    float* ws = (float*)d_ws;
    float* out = (float*)d_out;

    hipLaunchKernelGGL(k_prep, dim3(5), dim3(TPB), 0, stream,
                       state_inno, obs_inno, diff_state, diff_obs, lin_err, jac, ws);

    hipLaunchKernelGGL(k_l1l3, dim3(1280), dim3(TPB), 0, stream,
                       l1_W, l1_b, l3_W, l3_b, ws);

    hipLaunchKernelGGL(k_gates, dim3(3584), dim3(TPB), 0, stream,
                       g1Wih, g1bih, g2Wih, g2bih,
                       g1Whh, g1bhh, g2Whh, g2bhh, hn1, hn2, ws);

    hipLaunchKernelGGL(k_gru, dim3(16), dim3(TPB), 0, stream, hn1, hn2, ws);

    hipLaunchKernelGGL(k_stageD, dim3(1024), dim3(TPB), 0, stream,
                       l2_W1, l2_b1, l4_W1, l4_b1, ws);

    hipLaunchKernelGGL(k_stageE, dim3(1024), dim3(TPB), 0, stream,
                       l2_W2, l2_b2, l4_W2, l4_b2, ws, out);
}